// Round 3
// baseline (187.700 us; speedup 1.0000x reference)
//
#include <hip/hip_runtime.h>
#include <hip/hip_bf16.h>

typedef __bf16 bf16;
typedef __bf16 bf16x4 __attribute__((ext_vector_type(4)));
typedef __bf16 bf16x8 __attribute__((ext_vector_type(8)));
typedef float f32x4 __attribute__((ext_vector_type(4)));

// (1/16) * log2(e): softmax scale folded into exp2
#define SM_C 0.09016994374947424f

// ---------------------------------------------------------------------------
// prep: Wq/Wk/Wv/Wo [k][n] f32 -> Wt[mat][n][k] bf16 (B-operand layout)
// ---------------------------------------------------------------------------
__global__ __launch_bounds__(256) void transpose_w(
    const float* __restrict__ Wq, const float* __restrict__ Wk,
    const float* __restrict__ Wv, const float* __restrict__ Wo,
    bf16* __restrict__ Wt)
{
    int idx = blockIdx.x * 256 + threadIdx.x;   // 1024 blocks
    int m = idx >> 16, r = idx & 65535;
    int n = r >> 8, k = r & 255;
    const float* W = (m == 0) ? Wq : (m == 1) ? Wk : (m == 2) ? Wv : Wo;
    Wt[(size_t)m * 65536 + n * 256 + k] = (bf16)W[k * 256 + n];
}

// ---------------------------------------------------------------------------
// Fused QKV as ONE GEMM: C[32768][768] = X[32768][256] x W[256][768].
// grid (256 bm, 6 bn), 256 thr, 128x128 tile, BK=64, 37 KB LDS ->
// 3 blocks/CU co-resident: barriers/epilogue of one block hide under MFMA
// of the others (the structural fix vs the 1-block/CU 12-in-1 design).
// X converted f32->bf16 inline during staging (no pre-pass, X read once:
// bm-fastest ids put all 6 bn-panels of a row-panel on one XCD -> L2 reuse).
// V panel epilogue: 4 consecutive rows packed into one 8B store.
// ---------------------------------------------------------------------------
__global__ __launch_bounds__(256, 3) void qkv_gemm(
    const float* __restrict__ X, const bf16* __restrict__ Wt,
    const float* __restrict__ bq, const float* __restrict__ bk,
    const float* __restrict__ bv,
    bf16* __restrict__ Qo, bf16* __restrict__ Ko, bf16* __restrict__ Vto)
{
    __shared__ bf16 Xs[128 * 72];    // A tile: 128 rows x 64 k
    __shared__ bf16 Ws_[128 * 72];   // B tile: 128 n-rows x 64 k

    const int t    = threadIdx.x;
    const int lane = t & 63, wv = t >> 6;
    const int quad = lane >> 4, l16 = lane & 15;
    const int bm   = blockIdx.x;          // 0..255 (fastest -> XCD = bm%8)
    const int bn   = blockIdx.y;          // 0..5
    const int proj = bn >> 1;

    const bf16* W = Wt + (size_t)proj * 65536 + (size_t)(bn & 1) * 32768;
    const float* bias = (proj == 0) ? bq : (proj == 1) ? bk : bv;

    const int m0 = t >> 3;          // 0..31
    const int c0 = (t & 7) * 8;     // 0..56

    const f32x4 zero = {0.0f, 0.0f, 0.0f, 0.0f};
    f32x4 acc[2][8];
#pragma unroll
    for (int i = 0; i < 2; ++i)
#pragma unroll
        for (int j = 0; j < 8; ++j) acc[i][j] = zero;

    // prologue: load K-step 0
    f32x4 xa[4], xb[4]; bf16x8 wp[4];
#pragma unroll
    for (int p = 0; p < 4; ++p) {
        const float* px = X + (size_t)(bm * 128 + m0 + p * 32) * 256 + c0;
        xa[p] = *(const f32x4*)px; xb[p] = *(const f32x4*)(px + 4);
        wp[p] = *(const bf16x8*)(W + (size_t)(m0 + p * 32) * 256 + c0);
    }

    for (int kt = 0; kt < 4; ++kt) {
        // commit K-step kt to LDS
#pragma unroll
        for (int p = 0; p < 4; ++p) {
            bf16x8 r;
#pragma unroll
            for (int j = 0; j < 4; ++j) { r[j] = (bf16)xa[p][j]; r[j + 4] = (bf16)xb[p][j]; }
            *(bf16x8*)(Xs + (m0 + p * 32) * 72 + c0) = r;
            *(bf16x8*)(Ws_ + (m0 + p * 32) * 72 + c0) = wp[p];
        }
        __syncthreads();

        if (kt < 3) {   // issue next K-step loads; MFMA hides latency
#pragma unroll
            for (int p = 0; p < 4; ++p) {
                const float* px = X + (size_t)(bm * 128 + m0 + p * 32) * 256 + (kt + 1) * 64 + c0;
                xa[p] = *(const f32x4*)px; xb[p] = *(const f32x4*)(px + 4);
                wp[p] = *(const bf16x8*)(W + (size_t)(m0 + p * 32) * 256 + (kt + 1) * 64 + c0);
            }
        }

#pragma unroll
        for (int ks = 0; ks < 2; ++ks) {
            bf16x8 a[2], bb[8];
#pragma unroll
            for (int mt = 0; mt < 2; ++mt)
                a[mt] = *(const bf16x8*)(Xs + (wv * 32 + mt * 16 + l16) * 72 + ks * 32 + quad * 8);
#pragma unroll
            for (int nt = 0; nt < 8; ++nt)
                bb[nt] = *(const bf16x8*)(Ws_ + (nt * 16 + l16) * 72 + ks * 32 + quad * 8);
#pragma unroll
            for (int mt = 0; mt < 2; ++mt)
#pragma unroll
                for (int nt = 0; nt < 8; ++nt)
                    acc[mt][nt] = __builtin_amdgcn_mfma_f32_16x16x32_bf16(
                        a[mt], bb[nt], acc[mt][nt], 0, 0, 0);
        }
        __syncthreads();
    }

    // epilogue
#pragma unroll
    for (int nt = 0; nt < 8; ++nt) {
        int col = (bn & 1) * 128 + nt * 16 + l16;   // 0..255 within proj
        float bvv = bias[col];
#pragma unroll
        for (int mt = 0; mt < 2; ++mt) {
            int grow0 = bm * 128 + wv * 32 + mt * 16 + quad * 4;
            if (proj == 2) {
                // pack 4 consecutive rows -> one 8B store (col-major Vt)
                bf16x4 pk;
#pragma unroll
                for (int r = 0; r < 4; ++r) pk[r] = (bf16)(acc[mt][nt][r] + bvv);
                int b = grow0 >> 10, m = grow0 & 1023;
                *(bf16x4*)(Vto + (size_t)b * 262144 + (size_t)col * 1024 + m) = pk;
            } else {
                bf16* dst = (proj == 0) ? Qo : Ko;
#pragma unroll
                for (int r = 0; r < 4; ++r)
                    dst[(size_t)(grow0 + r) * 256 + col] = (bf16)(acc[mt][nt][r] + bvv);
            }
        }
    }
}

// ---------------------------------------------------------------------------
// Flash attention, 512 threads / 8 waves (2 waves/SIMD), grid (32 b, 8 qt).
// Each wave owns 16 q-rows; one shared K/V LDS copy feeds all 8 waves.
// Double-buffered K/V -> ONE barrier per KV tile; s_setprio(1) around both
// MFMA clusters (T5). P tile per wave [16][32] bf16, XOR-swizzled.
// ---------------------------------------------------------------------------
__global__ __launch_bounds__(512, 2) void flash_attn(
    const bf16* __restrict__ Qr, const bf16* __restrict__ K,
    const bf16* __restrict__ Vt, bf16* __restrict__ A)
{
    __shared__ bf16 Ks[2][32 * 264];   // [buf][kv][c], pad 256->264
    __shared__ bf16 Vs[2][256 * 40];   // [buf][c][kv], pad 32->40
    __shared__ bf16 Ps[8][16 * 32];    // per-wave P tile, XOR-swizzled

    const int t    = threadIdx.x;
    const int lane = t & 63, wv = t >> 6;          // wv 0..7
    const int quad = lane >> 4, l16 = lane & 15;
    const int b  = blockIdx.x;   // 0..31  (fastest -> XCD = b % 8)
    const int qt = blockIdx.y;   // 0..7

    // Q fragments: wave rows = qt*128 + wv*16 + l16
    bf16x8 qf[8];
    const size_t qrow = (size_t)b * 1024 + qt * 128 + wv * 16 + l16;
#pragma unroll
    for (int ks = 0; ks < 8; ++ks)
        qf[ks] = *(const bf16x8*)(Qr + qrow * 256 + ks * 32 + quad * 8);

    const f32x4 zero = {0.0f, 0.0f, 0.0f, 0.0f};
    f32x4 o[16];
#pragma unroll
    for (int n = 0; n < 16; ++n) o[n] = zero;
    float lst[4] = {0.f, 0.f, 0.f, 0.f};

    char* Pb = (char*)(Ps[wv]);

    // staging index split (512 threads, 2 x 16B each for K and V)
    const int kv0 = t >> 4, kc0 = (t & 15) * 8;   // K: row kv0, elems kc0 + p*128
    const int vc0 = t >> 1, vm0 = (t & 1) * 8;    // V: row vc0, elems vm0 + p*16

    bf16x8 kp[2], vp[2];
    // prologue: tile 0 -> buf 0; tile 1 loads in flight
#pragma unroll
    for (int p = 0; p < 2; ++p) {
        kp[p] = *(const bf16x8*)(K + (size_t)(b * 1024 + kv0) * 256 + kc0 + p * 128);
        vp[p] = *(const bf16x8*)(Vt + (size_t)b * 262144 + (size_t)vc0 * 1024 + vm0 + p * 16);
    }
#pragma unroll
    for (int p = 0; p < 2; ++p) {
        *(bf16x8*)(Ks[0] + kv0 * 264 + kc0 + p * 128) = kp[p];
        *(bf16x8*)(Vs[0] + vc0 * 40 + vm0 + p * 16) = vp[p];
    }
#pragma unroll
    for (int p = 0; p < 2; ++p) {
        kp[p] = *(const bf16x8*)(K + (size_t)(b * 1024 + 32 + kv0) * 256 + kc0 + p * 128);
        vp[p] = *(const bf16x8*)(Vt + (size_t)b * 262144 + (size_t)vc0 * 1024 + 32 + vm0 + p * 16);
    }

    for (int j = 0; j < 32; ++j) {
        const bf16* Kb = Ks[j & 1];
        const bf16* Vb = Vs[j & 1];
        __syncthreads();   // tile j stores visible; prior reads of buf^1 done

        // ---- S = Q K^T
        f32x4 s[2];
        s[0] = zero; s[1] = zero;
        __builtin_amdgcn_s_setprio(1);
#pragma unroll
        for (int ks = 0; ks < 8; ++ks) {
#pragma unroll
            for (int n = 0; n < 2; ++n) {
                bf16x8 bfr = *(const bf16x8*)(Kb + (n * 16 + l16) * 264 + ks * 32 + quad * 8);
                s[n] = __builtin_amdgcn_mfma_f32_16x16x32_bf16(qf[ks], bfr, s[n], 0, 0, 0);
            }
        }
        __builtin_amdgcn_s_setprio(0);

        // ---- commit tile j+1 into other buffer; issue tile j+2 loads
        if (j < 31) {
            bf16* Kn = Ks[(j + 1) & 1];
            bf16* Vn = Vs[(j + 1) & 1];
#pragma unroll
            for (int p = 0; p < 2; ++p) {
                *(bf16x8*)(Kn + kv0 * 264 + kc0 + p * 128) = kp[p];
                *(bf16x8*)(Vn + vc0 * 40 + vm0 + p * 16) = vp[p];
            }
            if (j < 30) {
#pragma unroll
                for (int p = 0; p < 2; ++p) {
                    kp[p] = *(const bf16x8*)(K + (size_t)(b * 1024 + (j + 2) * 32 + kv0) * 256 + kc0 + p * 128);
                    vp[p] = *(const bf16x8*)(Vt + (size_t)b * 262144 + (size_t)vc0 * 1024 + (j + 2) * 32 + vm0 + p * 16);
                }
            }
        }

        // ---- no-max softmax: p = exp2(s*SM_C); P -> XOR-swizzled LDS
#pragma unroll
        for (int n = 0; n < 2; ++n) {
#pragma unroll
            for (int r = 0; r < 4; ++r) {
                float pv = __builtin_amdgcn_exp2f(s[n][r] * SM_C);
                lst[r] += pv;
                int row = quad * 4 + r;
                *(bf16*)(Pb + ((row * 64 + n * 32 + l16 * 2) ^ ((row & 7) << 4))) = (bf16)pv;
            }
        }

        // ---- O += P V
        bf16x8 af = *(const bf16x8*)(Pb + ((l16 * 64 + quad * 16) ^ ((l16 & 7) << 4)));
        __builtin_amdgcn_s_setprio(1);
#pragma unroll
        for (int n = 0; n < 16; ++n) {
            bf16x8 bfr = *(const bf16x8*)(Vb + (n * 16 + l16) * 40 + quad * 8);
            o[n] = __builtin_amdgcn_mfma_f32_16x16x32_bf16(af, bfr, o[n], 0, 0, 0);
        }
        __builtin_amdgcn_s_setprio(0);
    }

    // ---- epilogue: reduce l across the 16-lane col group, normalize, store
#pragma unroll
    for (int r = 0; r < 4; ++r) {
        float l = lst[r];
        for (int off = 1; off < 16; off <<= 1)
            l += __shfl_xor(l, off, 64);
        float inv = 1.0f / l;
        size_t grow = (size_t)b * 1024 + qt * 128 + wv * 16 + quad * 4 + r;
#pragma unroll
        for (int n = 0; n < 16; ++n)
            A[grow * 256 + n * 16 + l16] = (bf16)(o[n][r] * inv);
    }
}

// ---------------------------------------------------------------------------
// O-projection: attended bf16 x pre-transposed Wo(bf16) -> f32 out.
// grid (256 bm, 4 nt). Register-prefetch pipeline across the 4 BK=64 steps.
// ---------------------------------------------------------------------------
__global__ __launch_bounds__(256) void oproj_gemm(
    const bf16* __restrict__ Xv, const bf16* __restrict__ W,
    const float* __restrict__ bias, float* __restrict__ outv)
{
    __shared__ bf16 Xs[128 * 72];
    __shared__ bf16 Ws[64 * 72];

    const int t    = threadIdx.x;
    const int lane = t & 63, wv = t >> 6;
    const int quad = lane >> 4, l16 = lane & 15;
    const int bm = blockIdx.x;
    const int bn = blockIdx.y;

    const f32x4 zero = {0.0f, 0.0f, 0.0f, 0.0f};
    f32x4 acc[2][4];
    for (int i = 0; i < 2; ++i)
        for (int j = 0; j < 4; ++j) acc[i][j] = zero;

    const int m0 = t >> 3;
    const int c0 = (t & 7) * 8;

    bf16x8 xp[4], wp[2];
#pragma unroll
    for (int p = 0; p < 4; ++p)
        xp[p] = *(const bf16x8*)(Xv + (size_t)(bm * 128 + m0 + p * 32) * 256 + c0);
#pragma unroll
    for (int p = 0; p < 2; ++p)
        wp[p] = *(const bf16x8*)(W + (size_t)(bn * 64 + m0 + p * 32) * 256 + c0);

    for (int kt = 0; kt < 4; ++kt) {
#pragma unroll
        for (int p = 0; p < 4; ++p)
            *(bf16x8*)(Xs + (m0 + p * 32) * 72 + c0) = xp[p];
#pragma unroll
        for (int p = 0; p < 2; ++p)
            *(bf16x8*)(Ws + (m0 + p * 32) * 72 + c0) = wp[p];
        __syncthreads();

        if (kt < 3) {
#pragma unroll
            for (int p = 0; p < 4; ++p)
                xp[p] = *(const bf16x8*)(Xv + (size_t)(bm * 128 + m0 + p * 32) * 256 + (kt + 1) * 64 + c0);
#pragma unroll
            for (int p = 0; p < 2; ++p)
                wp[p] = *(const bf16x8*)(W + (size_t)(bn * 64 + m0 + p * 32) * 256 + (kt + 1) * 64 + c0);
        }

#pragma unroll
        for (int ks = 0; ks < 2; ++ks) {
            bf16x8 a[2], bb[4];
            for (int mt = 0; mt < 2; ++mt)
                a[mt] = *(const bf16x8*)(Xs + (wv * 32 + mt * 16 + l16) * 72 + ks * 32 + quad * 8);
            for (int nt = 0; nt < 4; ++nt)
                bb[nt] = *(const bf16x8*)(Ws + (nt * 16 + l16) * 72 + ks * 32 + quad * 8);
            for (int mt = 0; mt < 2; ++mt)
                for (int nt = 0; nt < 4; ++nt)
                    acc[mt][nt] = __builtin_amdgcn_mfma_f32_16x16x32_bf16(
                        a[mt], bb[nt], acc[mt][nt], 0, 0, 0);
        }
        __syncthreads();
    }

#pragma unroll
    for (int nt = 0; nt < 4; ++nt) {
        int col = bn * 64 + nt * 16 + l16;
        float bvv = bias[col];
#pragma unroll
        for (int mt = 0; mt < 2; ++mt)
#pragma unroll
            for (int r = 0; r < 4; ++r) {
                int grow = bm * 128 + wv * 32 + mt * 16 + quad * 4 + r;
                outv[(size_t)grow * 256 + col] = acc[mt][nt][r] + bvv;
            }
    }
}

// ---------------------------------------------------------------------------
extern "C" void kernel_launch(void* const* d_in, const int* in_sizes, int n_in,
                              void* d_out, int out_size, void* d_ws, size_t ws_size,
                              hipStream_t stream)
{
    (void)in_sizes; (void)n_in; (void)out_size; (void)ws_size;
    const float* X  = (const float*)d_in[0];
    const float* Wq = (const float*)d_in[1];
    const float* bq = (const float*)d_in[2];
    const float* Wk = (const float*)d_in[3];
    const float* bk = (const float*)d_in[4];
    const float* Wv = (const float*)d_in[5];
    const float* bv = (const float*)d_in[6];
    const float* Wo = (const float*)d_in[7];
    const float* bo = (const float*)d_in[8];
    float* out = (float*)d_out;

    const size_t NTOK = (size_t)32768 * 256;

    // workspace: Wt (4 mats = 512 KB) + Q + K + Vt
    bf16* Wt  = (bf16*)d_ws;
    bf16* Qw  = (bf16*)d_ws + 262144;
    bf16* Kw  = Qw + NTOK;
    bf16* Vtw = Kw + NTOK;

    transpose_w<<<1024, 256, 0, stream>>>(Wq, Wk, Wv, Wo, Wt);
    qkv_gemm   <<<dim3(256, 6), 256, 0, stream>>>(X, Wt, bq, bk, bv, Qw, Kw, Vtw);
    flash_attn <<<dim3(32, 8),  512, 0, stream>>>(Qw, Kw, Vtw, Qw);  // in-place
    oproj_gemm <<<dim3(256, 4), 256, 0, stream>>>(Qw, Wt + 3 * 65536, bo, out);
}

// Round 4
// 181.789 us; speedup vs baseline: 1.0325x; 1.0325x over previous
//
#include <hip/hip_runtime.h>
#include <hip/hip_bf16.h>

typedef __bf16 bf16;
typedef __bf16 bf16x4 __attribute__((ext_vector_type(4)));
typedef __bf16 bf16x8 __attribute__((ext_vector_type(8)));
typedef float f32x4 __attribute__((ext_vector_type(4)));

// (1/16) * log2(e): softmax scale folded into exp2
#define SM_C 0.09016994374947424f

// ---------------------------------------------------------------------------
// prep: Wq/Wk/Wv/Wo [k][n] f32 -> Wt[mat][n][k] bf16 (B-operand layout)
// ---------------------------------------------------------------------------
__global__ __launch_bounds__(256) void transpose_w(
    const float* __restrict__ Wq, const float* __restrict__ Wk,
    const float* __restrict__ Wv, const float* __restrict__ Wo,
    bf16* __restrict__ Wt)
{
    int idx = blockIdx.x * 256 + threadIdx.x;   // 1024 blocks
    int m = idx >> 16, r = idx & 65535;
    int n = r >> 8, k = r & 255;
    const float* W = (m == 0) ? Wq : (m == 1) ? Wk : (m == 2) ? Wv : Wo;
    Wt[(size_t)m * 65536 + n * 256 + k] = (bf16)W[k * 256 + n];
}

// ---------------------------------------------------------------------------
// Fused QKV as ONE GEMM: C[32768][768] = X[32768][256] x W[256][768].
// grid (256 bm, 6 bn), 256 thr, 128x128 tile, BK=64, 37 KB LDS ->
// multiple blocks/CU co-resident. X converted f32->bf16 inline during
// staging. V panel epilogue: 4 consecutive rows packed into one 8B store.
// ---------------------------------------------------------------------------
__global__ __launch_bounds__(256, 3) void qkv_gemm(
    const float* __restrict__ X, const bf16* __restrict__ Wt,
    const float* __restrict__ bq, const float* __restrict__ bk,
    const float* __restrict__ bv,
    bf16* __restrict__ Qo, bf16* __restrict__ Ko, bf16* __restrict__ Vto)
{
    __shared__ bf16 Xs[128 * 72];    // A tile: 128 rows x 64 k
    __shared__ bf16 Ws_[128 * 72];   // B tile: 128 n-rows x 64 k

    const int t    = threadIdx.x;
    const int lane = t & 63, wv = t >> 6;
    const int quad = lane >> 4, l16 = lane & 15;
    const int bm   = blockIdx.x;          // 0..255 (fastest -> XCD = bm%8)
    const int bn   = blockIdx.y;          // 0..5
    const int proj = bn >> 1;

    const bf16* W = Wt + (size_t)proj * 65536 + (size_t)(bn & 1) * 32768;
    const float* bias = (proj == 0) ? bq : (proj == 1) ? bk : bv;

    const int m0 = t >> 3;          // 0..31
    const int c0 = (t & 7) * 8;     // 0..56

    const f32x4 zero = {0.0f, 0.0f, 0.0f, 0.0f};
    f32x4 acc[2][8];
#pragma unroll
    for (int i = 0; i < 2; ++i)
#pragma unroll
        for (int j = 0; j < 8; ++j) acc[i][j] = zero;

    // prologue: load K-step 0
    f32x4 xa[4], xb[4]; bf16x8 wp[4];
#pragma unroll
    for (int p = 0; p < 4; ++p) {
        const float* px = X + (size_t)(bm * 128 + m0 + p * 32) * 256 + c0;
        xa[p] = *(const f32x4*)px; xb[p] = *(const f32x4*)(px + 4);
        wp[p] = *(const bf16x8*)(W + (size_t)(m0 + p * 32) * 256 + c0);
    }

    for (int kt = 0; kt < 4; ++kt) {
        // commit K-step kt to LDS
#pragma unroll
        for (int p = 0; p < 4; ++p) {
            bf16x8 r;
#pragma unroll
            for (int j = 0; j < 4; ++j) { r[j] = (bf16)xa[p][j]; r[j + 4] = (bf16)xb[p][j]; }
            *(bf16x8*)(Xs + (m0 + p * 32) * 72 + c0) = r;
            *(bf16x8*)(Ws_ + (m0 + p * 32) * 72 + c0) = wp[p];
        }
        __syncthreads();

        if (kt < 3) {   // issue next K-step loads; MFMA hides latency
#pragma unroll
            for (int p = 0; p < 4; ++p) {
                const float* px = X + (size_t)(bm * 128 + m0 + p * 32) * 256 + (kt + 1) * 64 + c0;
                xa[p] = *(const f32x4*)px; xb[p] = *(const f32x4*)(px + 4);
                wp[p] = *(const bf16x8*)(W + (size_t)(m0 + p * 32) * 256 + (kt + 1) * 64 + c0);
            }
        }

#pragma unroll
        for (int ks = 0; ks < 2; ++ks) {
            bf16x8 a[2], bb[8];
#pragma unroll
            for (int mt = 0; mt < 2; ++mt)
                a[mt] = *(const bf16x8*)(Xs + (wv * 32 + mt * 16 + l16) * 72 + ks * 32 + quad * 8);
#pragma unroll
            for (int nt = 0; nt < 8; ++nt)
                bb[nt] = *(const bf16x8*)(Ws_ + (nt * 16 + l16) * 72 + ks * 32 + quad * 8);
#pragma unroll
            for (int mt = 0; mt < 2; ++mt)
#pragma unroll
                for (int nt = 0; nt < 8; ++nt)
                    acc[mt][nt] = __builtin_amdgcn_mfma_f32_16x16x32_bf16(
                        a[mt], bb[nt], acc[mt][nt], 0, 0, 0);
        }
        __syncthreads();
    }

    // epilogue
#pragma unroll
    for (int nt = 0; nt < 8; ++nt) {
        int col = (bn & 1) * 128 + nt * 16 + l16;   // 0..255 within proj
        float bvv = bias[col];
#pragma unroll
        for (int mt = 0; mt < 2; ++mt) {
            int grow0 = bm * 128 + wv * 32 + mt * 16 + quad * 4;
            if (proj == 2) {
                // pack 4 consecutive rows -> one 8B store (col-major Vt)
                bf16x4 pk;
#pragma unroll
                for (int r = 0; r < 4; ++r) pk[r] = (bf16)(acc[mt][nt][r] + bvv);
                int b = grow0 >> 10, m = grow0 & 1023;
                *(bf16x4*)(Vto + (size_t)b * 262144 + (size_t)col * 1024 + m) = pk;
            } else {
                bf16* dst = (proj == 0) ? Qo : Ko;
#pragma unroll
                for (int r = 0; r < 4; ++r)
                    dst[(size_t)(grow0 + r) * 256 + col] = (bf16)(acc[mt][nt][r] + bvv);
            }
        }
    }
}

// ---------------------------------------------------------------------------
// Flash attention + fused O-projection. 512 thr / 8 waves, grid (32 b, 8 qt).
// Main loop unchanged (double-buffered K/V, one barrier/iter, P XOR-swizzle;
// setprio reverted — it cost 3 us in round 3).
// Epilogue: normalized attended tile -> LDS (A-frag layout) over the dead
// Ks/Vs region; Wo staged in two 128-col halves over the dead Ps region;
// each wave computes a 64-row x 32-col strip per half; f32 out + bo written
// directly. Eliminates the oproj kernel and the 32 MB attended round-trip.
// LDS map (byte offsets in smem[142336]):
//   main loop:  Ks0=0(16896) Ks1=16896 Vs0=33792(20480) Vs1=54272 Ps=74752(8K)
//   epilogue:   Os=0(67584)  Wos=74752(67584)
// All overlaps barrier-protected (post-loop sync before Os overwrites K/V;
// sync pair around each Wo half restage).
// ---------------------------------------------------------------------------
__global__ __launch_bounds__(512, 2) void flash_attn(
    const bf16* __restrict__ Qr, const bf16* __restrict__ K,
    const bf16* __restrict__ Vt, const bf16* __restrict__ Wo,
    const float* __restrict__ bo, float* __restrict__ out)
{
    __shared__ __align__(16) char smem[142336];
    bf16* const Ksp0 = (bf16*)(smem);
    bf16* const Ksp1 = (bf16*)(smem + 16896);
    bf16* const Vsp0 = (bf16*)(smem + 33792);
    bf16* const Vsp1 = (bf16*)(smem + 54272);
    bf16* const Os   = (bf16*)(smem);
    bf16* const Wos  = (bf16*)(smem + 74752);

    const int t    = threadIdx.x;
    const int lane = t & 63, wv = t >> 6;          // wv 0..7
    const int quad = lane >> 4, l16 = lane & 15;
    const int b  = blockIdx.x;   // 0..31  (fastest -> XCD = b % 8)
    const int qt = blockIdx.y;   // 0..7

    char* const Pb = smem + 74752 + wv * 1024;     // per-wave P tile [16][32]

    // Q fragments: wave rows = qt*128 + wv*16 + l16
    bf16x8 qf[8];
    const size_t qrow = (size_t)b * 1024 + qt * 128 + wv * 16 + l16;
#pragma unroll
    for (int ks = 0; ks < 8; ++ks)
        qf[ks] = *(const bf16x8*)(Qr + qrow * 256 + ks * 32 + quad * 8);

    const f32x4 zero = {0.0f, 0.0f, 0.0f, 0.0f};
    f32x4 o[16];
#pragma unroll
    for (int n = 0; n < 16; ++n) o[n] = zero;
    float lst[4] = {0.f, 0.f, 0.f, 0.f};

    // staging index split (512 threads, 2 x 16B each for K and V)
    const int kv0 = t >> 4, kc0 = (t & 15) * 8;   // K: row kv0, elems kc0 + p*128
    const int vc0 = t >> 1, vm0 = (t & 1) * 8;    // V: row vc0, elems vm0 + p*16

    bf16x8 kp[2], vp[2];
    // prologue: tile 0 -> buf 0; tile 1 loads in flight
#pragma unroll
    for (int p = 0; p < 2; ++p) {
        kp[p] = *(const bf16x8*)(K + (size_t)(b * 1024 + kv0) * 256 + kc0 + p * 128);
        vp[p] = *(const bf16x8*)(Vt + (size_t)b * 262144 + (size_t)vc0 * 1024 + vm0 + p * 16);
    }
#pragma unroll
    for (int p = 0; p < 2; ++p) {
        *(bf16x8*)(Ksp0 + kv0 * 264 + kc0 + p * 128) = kp[p];
        *(bf16x8*)(Vsp0 + vc0 * 40 + vm0 + p * 16) = vp[p];
    }
#pragma unroll
    for (int p = 0; p < 2; ++p) {
        kp[p] = *(const bf16x8*)(K + (size_t)(b * 1024 + 32 + kv0) * 256 + kc0 + p * 128);
        vp[p] = *(const bf16x8*)(Vt + (size_t)b * 262144 + (size_t)vc0 * 1024 + 32 + vm0 + p * 16);
    }

    for (int j = 0; j < 32; ++j) {
        const bf16* Kb = (j & 1) ? Ksp1 : Ksp0;
        const bf16* Vb = (j & 1) ? Vsp1 : Vsp0;
        __syncthreads();   // tile j stores visible; prior reads of buf^1 done

        // ---- S = Q K^T
        f32x4 s[2];
        s[0] = zero; s[1] = zero;
#pragma unroll
        for (int ks = 0; ks < 8; ++ks) {
#pragma unroll
            for (int n = 0; n < 2; ++n) {
                bf16x8 bfr = *(const bf16x8*)(Kb + (n * 16 + l16) * 264 + ks * 32 + quad * 8);
                s[n] = __builtin_amdgcn_mfma_f32_16x16x32_bf16(qf[ks], bfr, s[n], 0, 0, 0);
            }
        }

        // ---- commit tile j+1 into other buffer; issue tile j+2 loads
        if (j < 31) {
            bf16* Kn = (j & 1) ? Ksp0 : Ksp1;
            bf16* Vn = (j & 1) ? Vsp0 : Vsp1;
#pragma unroll
            for (int p = 0; p < 2; ++p) {
                *(bf16x8*)(Kn + kv0 * 264 + kc0 + p * 128) = kp[p];
                *(bf16x8*)(Vn + vc0 * 40 + vm0 + p * 16) = vp[p];
            }
            if (j < 30) {
#pragma unroll
                for (int p = 0; p < 2; ++p) {
                    kp[p] = *(const bf16x8*)(K + (size_t)(b * 1024 + (j + 2) * 32 + kv0) * 256 + kc0 + p * 128);
                    vp[p] = *(const bf16x8*)(Vt + (size_t)b * 262144 + (size_t)vc0 * 1024 + (j + 2) * 32 + vm0 + p * 16);
                }
            }
        }

        // ---- no-max softmax: p = exp2(s*SM_C); P -> XOR-swizzled LDS
#pragma unroll
        for (int n = 0; n < 2; ++n) {
#pragma unroll
            for (int r = 0; r < 4; ++r) {
                float pv = __builtin_amdgcn_exp2f(s[n][r] * SM_C);
                lst[r] += pv;
                int row = quad * 4 + r;
                *(bf16*)(Pb + ((row * 64 + n * 32 + l16 * 2) ^ ((row & 7) << 4))) = (bf16)pv;
            }
        }

        // ---- O += P V
        bf16x8 af = *(const bf16x8*)(Pb + ((l16 * 64 + quad * 16) ^ ((l16 & 7) << 4)));
#pragma unroll
        for (int n = 0; n < 16; ++n) {
            bf16x8 bfr = *(const bf16x8*)(Vb + (n * 16 + l16) * 40 + quad * 8);
            o[n] = __builtin_amdgcn_mfma_f32_16x16x32_bf16(af, bfr, o[n], 0, 0, 0);
        }
    }

    __syncthreads();   // all PV reads of Ks/Vs done before Os overwrites them

    // ---- softmax denominators, normalized attended -> Os (A-frag layout)
    float inv[4];
#pragma unroll
    for (int r = 0; r < 4; ++r) {
        float l = lst[r];
#pragma unroll
        for (int off = 1; off < 16; off <<= 1)
            l += __shfl_xor(l, off, 64);
        inv[r] = 1.0f / l;
    }
#pragma unroll
    for (int n = 0; n < 16; ++n)
#pragma unroll
        for (int r = 0; r < 4; ++r)
            Os[(wv * 16 + quad * 4 + r) * 264 + n * 16 + l16] = (bf16)(o[n][r] * inv[r]);

    // ---- fused O-projection: out[128][256] = Os x Wo^T(+bo), two col-halves
    const int rh = (wv & 1) * 64;      // wave's row strip
    const int nq = wv >> 1;            // wave's 32-col strip within half
    const size_t orow0 = (size_t)b * 1024 + qt * 128 + rh;

#pragma unroll
    for (int h = 0; h < 2; ++h) {
        if (h) __syncthreads();        // previous half's Wos reads done
        // stage Wo half h: rows h*128..h*128+127 of Wo[n][k]
#pragma unroll
        for (int i = 0; i < 8; ++i) {
            int c = t + i * 512;
            int row = c >> 5, c8 = (c & 31) * 8;
            *(bf16x8*)(Wos + row * 264 + c8) =
                *(const bf16x8*)(Wo + (size_t)(h * 128 + row) * 256 + c8);
        }
        __syncthreads();               // Os (h==0) + Wos half visible

        f32x4 acc[4][2];
#pragma unroll
        for (int mt = 0; mt < 4; ++mt) { acc[mt][0] = zero; acc[mt][1] = zero; }

#pragma unroll
        for (int ks = 0; ks < 8; ++ks) {
            bf16x8 a[4], bb[2];
#pragma unroll
            for (int mt = 0; mt < 4; ++mt)
                a[mt] = *(const bf16x8*)(Os + (rh + mt * 16 + l16) * 264 + ks * 32 + quad * 8);
#pragma unroll
            for (int nt = 0; nt < 2; ++nt)
                bb[nt] = *(const bf16x8*)(Wos + (nq * 32 + nt * 16 + l16) * 264 + ks * 32 + quad * 8);
#pragma unroll
            for (int mt = 0; mt < 4; ++mt)
#pragma unroll
                for (int nt = 0; nt < 2; ++nt)
                    acc[mt][nt] = __builtin_amdgcn_mfma_f32_16x16x32_bf16(
                        a[mt], bb[nt], acc[mt][nt], 0, 0, 0);
        }

#pragma unroll
        for (int nt = 0; nt < 2; ++nt) {
            int col = h * 128 + nq * 32 + nt * 16 + l16;
            float bvv = bo[col];
#pragma unroll
            for (int mt = 0; mt < 4; ++mt) {
#pragma unroll
                for (int r = 0; r < 4; ++r) {
                    size_t row = orow0 + mt * 16 + quad * 4 + r;
                    out[row * 256 + col] = acc[mt][nt][r] + bvv;
                }
            }
        }
    }
}

// ---------------------------------------------------------------------------
extern "C" void kernel_launch(void* const* d_in, const int* in_sizes, int n_in,
                              void* d_out, int out_size, void* d_ws, size_t ws_size,
                              hipStream_t stream)
{
    (void)in_sizes; (void)n_in; (void)out_size; (void)ws_size;
    const float* X  = (const float*)d_in[0];
    const float* Wq = (const float*)d_in[1];
    const float* bq = (const float*)d_in[2];
    const float* Wk = (const float*)d_in[3];
    const float* bk = (const float*)d_in[4];
    const float* Wv = (const float*)d_in[5];
    const float* bv = (const float*)d_in[6];
    const float* Wo = (const float*)d_in[7];
    const float* bo = (const float*)d_in[8];
    float* out = (float*)d_out;

    const size_t NTOK = (size_t)32768 * 256;

    // workspace: Wt (4 mats = 512 KB) + Q + K + Vt
    bf16* Wt  = (bf16*)d_ws;
    bf16* Qw  = (bf16*)d_ws + 262144;
    bf16* Kw  = Qw + NTOK;
    bf16* Vtw = Kw + NTOK;

    transpose_w<<<1024, 256, 0, stream>>>(Wq, Wk, Wv, Wo, Wt);
    qkv_gemm   <<<dim3(256, 6), 256, 0, stream>>>(X, Wt, bq, bk, bv, Qw, Kw, Vtw);
    flash_attn <<<dim3(32, 8),  512, 0, stream>>>(Qw, Kw, Vtw, Wt + 3 * 65536, bo, out);
}